// Round 7
// baseline (135.934 us; speedup 1.0000x reference)
//
#include <hip/hip_runtime.h>
#include <cstdint>
#include <cstddef>
#include <math.h>

#define CAP 2048
#define KMAX 64
#define NEG_INF (-3.402823466e+38f)

// One block per row. ALL selection in f32 SCALED space (xs = x / t, f32
// correctly-rounded elementwise — identical to numpy), sort by
// (scaled desc, idx asc) == stable argsort(-xs). Top-k keeps ties of the
// kth value (mirrors `x < kth` filter). Softmax denominator mirrors
// numpy pairwise-8 summation over the first 128-leaf; cdf is f32 cumsum
// of f32 p_j; cutoff compares against the RAW f32 top_p.
__global__ __launch_bounds__(1024) void k_row(
        const float* __restrict__ in, float* __restrict__ out,
        const float* __restrict__ tempP, const int* __restrict__ topkP,
        const float* __restrict__ toppP, int V, int nv4) {
    __shared__ float s_red[1024];
    __shared__ float s_cv[CAP];
    __shared__ unsigned int s_ci[CAP];
    __shared__ unsigned int s_cnt;
    __shared__ float s_p[KMAX];
    __shared__ int s_kp;

    const int row = blockIdx.x;
    const int tid = (int)threadIdx.x;
    const int nthr = (int)blockDim.x;  // 1024

    const float t = tempP[0];
    const bool doT = (t > 0.f);
    int topk = topkP[0];
    if (topk < 0 || topk > V) topk = 0;
    const float topp = toppP[0];     // raw f32(0.9) = 0.899999976...

    // ---- sweep 1: zero output row, row max of SCALED logits ----
    const float4* in4 = (const float4*)in + (size_t)row * nv4;
    float4* out4 = (float4*)out + (size_t)row * nv4;
    float m = NEG_INF;
    for (int i = tid; i < nv4; i += nthr) {
        float4 v = in4[i];
        out4[i] = make_float4(0.f, 0.f, 0.f, 0.f);
        float a = doT ? v.x / t : v.x;
        float b = doT ? v.y / t : v.y;
        float c = doT ? v.z / t : v.z;
        float d = doT ? v.w / t : v.w;
        m = fmaxf(m, fmaxf(fmaxf(a, b), fmaxf(c, d)));
    }
    s_red[tid] = m;
    __syncthreads();
    for (int s = 512; s > 0; s >>= 1) {
        if (tid < s) s_red[tid] = fmaxf(s_red[tid], s_red[tid + s]);
        __syncthreads();
    }
    const float M = s_red[0];
    __syncthreads();

    const int kwant = (topk > 0) ? min(topk, KMAX) : KMAX;

    // ---- adaptive candidate collection in scaled space: xs >= M - dcut ----
    float dcut = 2.5f;
    unsigned int cnt = 0;
    for (int round = 0; round < 14; ++round) {
        if (tid == 0) s_cnt = 0u;
        __syncthreads();
        const float T = M - dcut;
        for (int i = tid; i < nv4; i += nthr) {
            float4 v = in4[i];
            float xs[4];
            xs[0] = doT ? v.x / t : v.x;
            xs[1] = doT ? v.y / t : v.y;
            xs[2] = doT ? v.z / t : v.z;
            xs[3] = doT ? v.w / t : v.w;
            #pragma unroll
            for (int c2 = 0; c2 < 4; ++c2) {
                if (xs[c2] >= T) {
                    unsigned int slot = atomicAdd(&s_cnt, 1u);
                    if (slot < (unsigned)CAP) {
                        s_cv[slot] = xs[c2];
                        s_ci[slot] = (unsigned int)(4 * i + c2);
                    }
                }
            }
        }
        __syncthreads();
        cnt = s_cnt;
        __syncthreads();
        if (cnt >= (unsigned)kwant && cnt <= (unsigned)CAP) break;
        if (round == 13) break;
        dcut = (cnt < (unsigned)kwant) ? (dcut * 2.0f) : (dcut * 0.4f);
    }
    const int ncand = (int)min(cnt, (unsigned)CAP);

    // pad to CAP with sentinels that sort to the end
    for (int s = ncand + tid; s < CAP; s += nthr) {
        s_cv[s] = NEG_INF;
        s_ci[s] = 0xFFFFFFFFu;
    }
    __syncthreads();

    // ---- bitonic sort: scaled value desc, index asc (== stable argsort(-xs)) ----
    for (unsigned int size = 2; size <= (unsigned)CAP; size <<= 1) {
        for (unsigned int stride = size >> 1; stride > 0; stride >>= 1) {
            for (int i = tid; i < CAP / 2; i += nthr) {
                unsigned int ui = (unsigned int)i;
                unsigned int pos = 2u * ui - (ui & (stride - 1u));
                unsigned int a = pos, b = pos + stride;
                float va = s_cv[a], vb = s_cv[b];
                unsigned int ia = s_ci[a], ib = s_ci[b];
                bool aBeforeB = (va > vb) || (va == vb && ia < ib);
                bool bBeforeA = (vb > va) || (vb == va && ib < ia);
                bool descBlock = ((pos & size) == 0u);
                bool doSwap = descBlock ? bBeforeA : aBeforeB;
                if (doSwap) {
                    s_cv[a] = vb; s_cv[b] = va;
                    s_ci[a] = ib; s_ci[b] = ia;
                }
            }
            __syncthreads();
        }
    }

    // ---- thread 0: f32-faithful top-k(+ties) and nucleus ----
    if (tid == 0) {
        int kp = 0;
        if (ncand > 0) {
            // top-k filter `x < kth` keeps ALL tokens with xs == kth
            int klim = min(kwant, ncand);
            if (topk > 0 && ncand >= kwant) {
                const float kth = s_cv[kwant - 1];
                while (klim < ncand && klim < KMAX && s_cv[klim] == kth) klim++;
            }
            // e_j = f32 correctly-rounded exp(sv_j - sv_0)
            const float sv0 = s_cv[0];
            float e[KMAX];
            for (int j = 0; j < klim; ++j)
                e[j] = (float)exp((double)(s_cv[j] - sv0));
            // S: numpy pairwise-8 over the first 128-leaf (zeros beyond klim)
            float r[8] = {0.f, 0.f, 0.f, 0.f, 0.f, 0.f, 0.f, 0.f};
            for (int i = 0; i < 128; i += 8)
                #pragma unroll
                for (int j2 = 0; j2 < 8; ++j2) {
                    int idx = i + j2;
                    if (idx < klim) r[j2] = r[j2] + e[idx];
                }
            const float S = ((r[0] + r[1]) + (r[2] + r[3])) +
                            ((r[4] + r[5]) + (r[6] + r[7]));
            // sequential f32 cumsum of f32 p_j; keep j iff j==0 or cdf[j-1] <= p
            if (topp > 0.f) {
                float cdf = 0.f;
                for (int j = 0; j < klim; ++j) {
                    if (j > 0 && cdf > topp) break;
                    kp++;
                    cdf = cdf + (float)(e[j] / S);
                }
            } else {
                kp = klim;
            }
            // final probs over kept set
            float D = 0.f;
            for (int j = 0; j < kp; ++j) D = D + e[j];
            if (!(D > 0.f)) D = 1.f;
            for (int j = 0; j < kp; ++j) s_p[j] = e[j] / D;
        }
        s_kp = kp;
    }
    __syncthreads();

    // ---- scatter kept probabilities ----
    if (tid < s_kp) {
        unsigned int tok = s_ci[tid];
        if (tok < (unsigned int)V)
            out[(size_t)row * V + tok] = s_p[tid];
    }
}

extern "C" void kernel_launch(void* const* d_in, const int* in_sizes, int n_in,
                              void* d_out, int out_size, void* d_ws, size_t ws_size,
                              hipStream_t stream) {
    const float* in = (const float*)d_in[0];
    const float* tempP = (const float*)d_in[2];
    const int* topkP = (const int*)d_in[3];
    const float* toppP = (const float*)d_in[4];
    float* out = (float*)d_out;

    int B = (n_in > 1 && in_sizes[1] > 0) ? in_sizes[1] : 128;
    int V = in_sizes[0] / B;
    int nv4 = V / 4;

    k_row<<<B, 1024, 0, stream>>>(in, out, tempP, topkP, toppP, V, nv4);
}